// Round 1
// baseline (1199.763 us; speedup 1.0000x reference)
//
#include <hip/hip_runtime.h>

#define FIN 128
#define FH  16
#define FO  64

// ---------- degree / norm ----------
__global__ void k_deg_init(float* __restrict__ deg, int n) {
    int i = blockIdx.x * blockDim.x + threadIdx.x;
    if (i < n) deg[i] = 1.0f;  // self-loop
}

__global__ void k_deg_edge(const int* __restrict__ dst, float* __restrict__ deg, int E) {
    int e = blockIdx.x * blockDim.x + threadIdx.x;
    if (e < E) atomicAdd(&deg[dst[e]], 1.0f);
}

__global__ void k_dinv(float* __restrict__ deg, int n) {
    int i = blockIdx.x * blockDim.x + threadIdx.x;
    if (i < n) deg[i] = rsqrtf(deg[i]);
}

// ---------- layer 1 transform: hs1 = (x @ W1) * dinv ; agg1 = hs1 (self-loop) ----------
__global__ __launch_bounds__(256) void k_gemm1(const float* __restrict__ x,
                                               const float* __restrict__ W1,
                                               const float* __restrict__ dinv,
                                               float* __restrict__ hs1,
                                               float* __restrict__ agg1, int n) {
    __shared__ float w[FIN * FH];  // 8 KB
    int t = threadIdx.x;
    for (int i = t; i < FIN * FH; i += 256) w[i] = W1[i];
    __syncthreads();
    int r = t >> 4, j = t & 15;
    int row = blockIdx.x * 16 + r;
    if (row >= n) return;
    const float* xr = x + (long long)row * FIN;
    float acc = 0.0f;
#pragma unroll 8
    for (int k = 0; k < FIN; ++k) acc = fmaf(xr[k], w[k * FH + j], acc);
    float v = acc * dinv[row];
    hs1[row * FH + j] = v;
    agg1[row * FH + j] = v;
}

// ---------- layer 1 edge scatter: agg1[dst] += hs1[src] ----------
__global__ __launch_bounds__(256) void k_agg1(const int* __restrict__ src,
                                              const int* __restrict__ dst,
                                              const float* __restrict__ hs1,
                                              float* __restrict__ agg1, int E) {
    int idx = blockIdx.x * blockDim.x + threadIdx.x;  // E*16 = 51.2M < 2^31
    if (idx >= E * FH) return;
    int e = idx >> 4, f = idx & 15;
    atomicAdd(&agg1[dst[e] * FH + f], hs1[src[e] * FH + f]);
}

// ---------- layer 1 finish + layer 2 transform ----------
// h1 = relu(dinv*agg1 + b1); hs2 = (h1 @ W2) * dinv ; out = hs2 (self-loop init)
__global__ __launch_bounds__(256) void k_mid(const float* __restrict__ agg1,
                                             const float* __restrict__ b1,
                                             const float* __restrict__ W2,
                                             const float* __restrict__ dinv,
                                             float* __restrict__ hs2,
                                             float* __restrict__ out, int n) {
    __shared__ float w[FH * FO];  // 4 KB
    __shared__ float h[4][FH];
    int t = threadIdx.x;
    for (int i = t; i < FH * FO; i += 256) w[i] = W2[i];
    int r = t >> 6, f = t & 63;
    int row = blockIdx.x * 4 + r;
    bool valid = row < n;
    if (valid && f < FH) {
        h[r][f] = fmaxf(fmaf(dinv[row], agg1[row * FH + f], b1[f]), 0.0f);
    }
    __syncthreads();
    if (!valid) return;
    float acc = 0.0f;
#pragma unroll
    for (int j = 0; j < FH; ++j) acc = fmaf(h[r][j], w[j * FO + f], acc);
    float v = acc * dinv[row];
    hs2[row * FO + f] = v;
    out[row * FO + f] = v;
}

// ---------- layer 2 edge scatter: out[dst] += hs2[src] ----------
__global__ __launch_bounds__(256) void k_agg2(const int* __restrict__ src,
                                              const int* __restrict__ dst,
                                              const float* __restrict__ hs2,
                                              float* __restrict__ out, int E) {
    int idx = blockIdx.x * blockDim.x + threadIdx.x;  // E*64 = 204.8M < 2^31
    if (idx >= E * FO) return;
    int e = idx >> 6, f = idx & 63;
    atomicAdd(&out[dst[e] * FO + f], hs2[src[e] * FO + f]);
}

// ---------- finalize: v = dinv*agg + b2, then row-wise log_softmax (one wave per row) ----------
__global__ __launch_bounds__(256) void k_final(const float* __restrict__ dinv,
                                               const float* __restrict__ b2,
                                               float* __restrict__ out, int n) {
    int t = threadIdx.x;
    int lane = t & 63;
    int row = blockIdx.x * 4 + (t >> 6);
    if (row >= n) return;
    float v = fmaf(dinv[row], out[row * FO + lane], b2[lane]);
    float m = v;
#pragma unroll
    for (int off = 32; off >= 1; off >>= 1) m = fmaxf(m, __shfl_xor(m, off, 64));
    float ex = __expf(v - m);
#pragma unroll
    for (int off = 32; off >= 1; off >>= 1) ex += __shfl_xor(ex, off, 64);
    out[row * FO + lane] = v - m - __logf(ex);
}

extern "C" void kernel_launch(void* const* d_in, const int* in_sizes, int n_in,
                              void* d_out, int out_size, void* d_ws, size_t ws_size,
                              hipStream_t stream) {
    const float* x  = (const float*)d_in[0];
    const int*   ei = (const int*)d_in[1];
    const float* W1 = (const float*)d_in[2];
    const float* b1 = (const float*)d_in[3];
    const float* W2 = (const float*)d_in[4];
    const float* b2 = (const float*)d_in[5];
    float* out = (float*)d_out;

    int N = in_sizes[0] / FIN;   // 100000
    int E = in_sizes[1] / 2;     // 3200000
    const int* src = ei;
    const int* dst = ei + E;

    // workspace layout (floats): dinv[N] | hs1[16N] | agg1[16N] | hs2[64N]  = 97N floats ~ 38.8 MB
    float* ws   = (float*)d_ws;
    float* dinv = ws;
    float* hs1  = ws + (long long)N;
    float* agg1 = ws + 17LL * N;
    float* hs2  = ws + 33LL * N;

    k_deg_init<<<(N + 255) / 256, 256, 0, stream>>>(dinv, N);
    k_deg_edge<<<(E + 255) / 256, 256, 0, stream>>>(dst, dinv, E);
    k_dinv<<<(N + 255) / 256, 256, 0, stream>>>(dinv, N);

    k_gemm1<<<(N + 15) / 16, 256, 0, stream>>>(x, W1, dinv, hs1, agg1, N);
    k_agg1<<<(E * FH + 255) / 256, 256, 0, stream>>>(src, dst, hs1, agg1, E);
    k_mid<<<(N + 3) / 4, 256, 0, stream>>>(agg1, b1, W2, dinv, hs2, out, N);
    k_agg2<<<(E * FO + 255) / 256, 256, 0, stream>>>(src, dst, hs2, out, E);
    k_final<<<(N + 3) / 4, 256, 0, stream>>>(dinv, b2, out, N);
}

// Round 2
// 759.128 us; speedup vs baseline: 1.5804x; 1.5804x over previous
//
#include <hip/hip_runtime.h>

#define FIN 128
#define FH  16
#define FO  64
#define SCAN_B 256

// ---------- counting sort by dst: histogram ----------
__global__ void k_zero(int* __restrict__ counts, int n) {
    int i = blockIdx.x * blockDim.x + threadIdx.x;
    if (i < n) counts[i] = 0;
}

__global__ void k_hist(const int* __restrict__ dst, int* __restrict__ counts, int E) {
    int e = blockIdx.x * blockDim.x + threadIdx.x;
    if (e < E) atomicAdd(&counts[dst[e]], 1);
}

// dinv[i] = rsqrt(in_degree + self_loop)
__global__ void k_dinv(const int* __restrict__ counts, float* __restrict__ dinv, int n) {
    int i = blockIdx.x * blockDim.x + threadIdx.x;
    if (i < n) dinv[i] = rsqrtf((float)(counts[i] + 1));
}

// block-level inclusive scan -> exclusive per-element, block totals to partials
__global__ __launch_bounds__(SCAN_B) void k_scan1(const int* __restrict__ counts,
                                                  int* __restrict__ row_start,
                                                  int* __restrict__ partials, int n) {
    __shared__ int s[SCAN_B];
    int t = threadIdx.x;
    int i = blockIdx.x * SCAN_B + t;
    int v = (i < n) ? counts[i] : 0;
    s[t] = v;
    __syncthreads();
    for (int off = 1; off < SCAN_B; off <<= 1) {
        int u = (t >= off) ? s[t - off] : 0;
        __syncthreads();
        s[t] += u;
        __syncthreads();
    }
    if (i < n) row_start[i] = s[t] - v;  // exclusive
    if (t == SCAN_B - 1) partials[blockIdx.x] = s[t];
}

// single-block scan of partials (nb <= 512) -> exclusive
__global__ __launch_bounds__(512) void k_scan2(int* __restrict__ partials, int nb) {
    __shared__ int s[512];
    int t = threadIdx.x;
    int v = (t < nb) ? partials[t] : 0;
    s[t] = v;
    __syncthreads();
    for (int off = 1; off < 512; off <<= 1) {
        int u = (t >= off) ? s[t - off] : 0;
        __syncthreads();
        s[t] += u;
        __syncthreads();
    }
    if (t < nb) partials[t] = s[t] - v;  // exclusive
}

__global__ void k_scan3(int* __restrict__ row_start, const int* __restrict__ partials,
                        int* __restrict__ fill_ptr, int n) {
    int i = blockIdx.x * blockDim.x + threadIdx.x;
    if (i < n) {
        int r = row_start[i] + partials[i / SCAN_B];
        row_start[i] = r;
        fill_ptr[i] = r;
    }
}

__global__ void k_scatter(const int* __restrict__ src, const int* __restrict__ dst,
                          int* __restrict__ fill_ptr, int* __restrict__ sorted_src, int E) {
    int e = blockIdx.x * blockDim.x + threadIdx.x;
    if (e < E) {
        int pos = atomicAdd(&fill_ptr[dst[e]], 1);
        sorted_src[pos] = src[e];
    }
}

// ---------- layer 1 transform: hs1 = (x @ W1) * dinv ----------
__global__ __launch_bounds__(256) void k_gemm1(const float* __restrict__ x,
                                               const float* __restrict__ W1,
                                               const float* __restrict__ dinv,
                                               float* __restrict__ hs1, int n) {
    __shared__ float w[FIN * FH];  // 8 KB
    int t = threadIdx.x;
    for (int i = t; i < FIN * FH; i += 256) w[i] = W1[i];
    __syncthreads();
    int r = t >> 4, j = t & 15;
    int row = blockIdx.x * 16 + r;
    if (row >= n) return;
    const float* xr = x + (long long)row * FIN;
    float acc = 0.0f;
#pragma unroll 8
    for (int k = 0; k < FIN; ++k) acc = fmaf(xr[k], w[k * FH + j], acc);
    hs1[row * FH + j] = acc * dinv[row];
}

// ---------- layer 1 gather + relu + bias: h1 = relu(dinv*(self + sum_in) + b1) ----------
// one wave per node: 4 sub-groups of 16 lanes each process every 4th edge
__global__ __launch_bounds__(256) void k_gather1(const int* __restrict__ rs,
                                                 const int* __restrict__ cnt,
                                                 const int* __restrict__ ss,
                                                 const float* __restrict__ hs1,
                                                 const float* __restrict__ dinv,
                                                 const float* __restrict__ b1,
                                                 float* __restrict__ h1, int n) {
    int t = threadIdx.x;
    int lane = t & 63, g = lane >> 4, f = lane & 15;
    int node = blockIdx.x * 4 + (t >> 6);
    if (node >= n) return;
    int beg = rs[node], end = beg + cnt[node];
    float acc = 0.0f;
    for (int e = beg + g; e < end; e += 4) acc += hs1[ss[e] * FH + f];
    acc += __shfl_xor(acc, 16, 64);
    acc += __shfl_xor(acc, 32, 64);
    acc += hs1[node * FH + f];  // self-loop
    float v = fmaxf(fmaf(dinv[node], acc, b1[f]), 0.0f);
    if (g == 0) h1[node * FH + f] = v;
}

// ---------- layer 2 transform: hs2 = (h1 @ W2) * dinv ----------
__global__ __launch_bounds__(256) void k_gemm2(const float* __restrict__ h1,
                                               const float* __restrict__ W2,
                                               const float* __restrict__ dinv,
                                               float* __restrict__ hs2, int n) {
    __shared__ float w[FH * FO];  // 4 KB
    __shared__ float h[4][FH];
    int t = threadIdx.x;
    for (int i = t; i < FH * FO; i += 256) w[i] = W2[i];
    int r = t >> 6, f = t & 63;
    int row = blockIdx.x * 4 + r;
    bool valid = row < n;
    if (valid && f < FH) h[r][f] = h1[row * FH + f];
    __syncthreads();
    if (!valid) return;
    float acc = 0.0f;
#pragma unroll
    for (int j = 0; j < FH; ++j) acc = fmaf(h[r][j], w[j * FO + f], acc);
    hs2[row * FO + f] = acc * dinv[row];
}

// ---------- layer 2 gather + bias + log_softmax ----------
// one wave per node, 64 lanes = 64 feats; unroll edge loop 4x for MLP
__global__ __launch_bounds__(256) void k_gather2(const int* __restrict__ rs,
                                                 const int* __restrict__ cnt,
                                                 const int* __restrict__ ss,
                                                 const float* __restrict__ hs2,
                                                 const float* __restrict__ dinv,
                                                 const float* __restrict__ b2,
                                                 float* __restrict__ out, int n) {
    int t = threadIdx.x;
    int lane = t & 63;
    int node = blockIdx.x * 4 + (t >> 6);
    if (node >= n) return;
    int beg = rs[node], end = beg + cnt[node];
    float acc = hs2[node * FO + lane];  // self-loop
    int e = beg;
    for (; e + 4 <= end; e += 4) {
        int s0 = ss[e], s1 = ss[e + 1], s2 = ss[e + 2], s3 = ss[e + 3];
        float v0 = hs2[s0 * FO + lane];
        float v1 = hs2[s1 * FO + lane];
        float v2 = hs2[s2 * FO + lane];
        float v3 = hs2[s3 * FO + lane];
        acc += (v0 + v1) + (v2 + v3);
    }
    for (; e < end; ++e) acc += hs2[ss[e] * FO + lane];
    float v = fmaf(dinv[node], acc, b2[lane]);
    float m = v;
#pragma unroll
    for (int off = 32; off >= 1; off >>= 1) m = fmaxf(m, __shfl_xor(m, off, 64));
    float ex = __expf(v - m);
#pragma unroll
    for (int off = 32; off >= 1; off >>= 1) ex += __shfl_xor(ex, off, 64);
    out[node * FO + lane] = v - m - __logf(ex);
}

extern "C" void kernel_launch(void* const* d_in, const int* in_sizes, int n_in,
                              void* d_out, int out_size, void* d_ws, size_t ws_size,
                              hipStream_t stream) {
    const float* x  = (const float*)d_in[0];
    const int*   ei = (const int*)d_in[1];
    const float* W1 = (const float*)d_in[2];
    const float* b1 = (const float*)d_in[3];
    const float* W2 = (const float*)d_in[4];
    const float* b2 = (const float*)d_in[5];
    float* out = (float*)d_out;

    int N = in_sizes[0] / FIN;   // 100000
    int E = in_sizes[1] / 2;     // 3200000
    const int* src = ei;
    const int* dst = ei + E;

    // workspace: ints first, then floats
    int*   counts     = (int*)d_ws;              // N
    int*   row_start  = counts + N;              // N
    int*   fill_ptr   = row_start + N;           // N
    int*   partials   = fill_ptr + N;            // 512
    int*   sorted_src = partials + 512;          // E
    float* dinv = (float*)(sorted_src + E);      // N
    float* hs1  = dinv + N;                      // 16N
    float* h1   = hs1 + 16LL * N;                // 16N
    float* hs2  = h1 + 16LL * N;                 // 64N

    int nb = (N + SCAN_B - 1) / SCAN_B;          // 391 <= 512

    k_zero<<<(N + 255) / 256, 256, 0, stream>>>(counts, N);
    k_hist<<<(E + 255) / 256, 256, 0, stream>>>(dst, counts, E);
    k_dinv<<<(N + 255) / 256, 256, 0, stream>>>(counts, dinv, N);
    k_scan1<<<nb, SCAN_B, 0, stream>>>(counts, row_start, partials, N);
    k_scan2<<<1, 512, 0, stream>>>(partials, nb);
    k_scan3<<<(N + 255) / 256, 256, 0, stream>>>(row_start, partials, fill_ptr, N);
    k_scatter<<<(E + 255) / 256, 256, 0, stream>>>(src, dst, fill_ptr, sorted_src, E);

    k_gemm1<<<(N + 15) / 16, 256, 0, stream>>>(x, W1, dinv, hs1, N);
    k_gather1<<<(N + 3) / 4, 256, 0, stream>>>(row_start, counts, sorted_src, hs1, dinv, b1, h1, N);
    k_gemm2<<<(N + 3) / 4, 256, 0, stream>>>(h1, W2, dinv, hs2, N);
    k_gather2<<<(N + 3) / 4, 256, 0, stream>>>(row_start, counts, sorted_src, hs2, dinv, b2, out, N);
}

// Round 3
// 513.262 us; speedup vs baseline: 2.3375x; 1.4790x over previous
//
#include <hip/hip_runtime.h>

#define FIN 128
#define FH  16
#define FO  64
#define GB  128        // nodes per bucket (pow2: bucket = dst>>7)
#define MAXNB 1024     // max buckets (N <= 131072)
#define CHUNK 8192     // edges per block in phase A3
#define STAGE 8192     // LDS staging capacity in phase B (mean bucket = 4092)

__global__ void k_zero(int* __restrict__ p, int n) {
    int i = blockIdx.x * blockDim.x + threadIdx.x;
    if (i < n) p[i] = 0;
}

// ---------- A1: bucket histogram (LDS-aggregated) ----------
__global__ __launch_bounds__(256) void k_bhist(const int* __restrict__ dst,
                                               int* __restrict__ bcnt, int E, int nb) {
    __shared__ int h[MAXNB];
    int t = threadIdx.x;
    for (int i = t; i < nb; i += 256) h[i] = 0;
    __syncthreads();
    int stride = gridDim.x * 256;
    for (int e = blockIdx.x * 256 + t; e < E; e += stride)
        atomicAdd(&h[dst[e] >> 7], 1);
    __syncthreads();
    for (int i = t; i < nb; i += 256)
        if (h[i]) atomicAdd(&bcnt[i], h[i]);
}

// ---------- A2: single-block exclusive scan of bucket counts ----------
__global__ __launch_bounds__(1024) void k_bscan(const int* __restrict__ bcnt,
                                                int* __restrict__ bstart,
                                                int* __restrict__ bfill, int nb) {
    __shared__ int s[1024];
    int t = threadIdx.x;
    int v = (t < nb) ? bcnt[t] : 0;
    s[t] = v;
    __syncthreads();
    for (int off = 1; off < 1024; off <<= 1) {
        int u = (t >= off) ? s[t - off] : 0;
        __syncthreads();
        s[t] += u;
        __syncthreads();
    }
    if (t < nb) { bstart[t] = s[t] - v; bfill[t] = s[t] - v; }
    if (t == nb - 1) bstart[nb] = s[t];
}

// ---------- A3: scatter packed edges into bucket segments ----------
// pack: (dst & 127) << 17 | src   (src < 2^17)
__global__ __launch_bounds__(256) void k_bscatter(const int* __restrict__ src,
                                                  const int* __restrict__ dst,
                                                  int* __restrict__ bfill,
                                                  int* __restrict__ bedge, int E, int nb) {
    __shared__ int h[MAXNB];
    __shared__ int base[MAXNB];
    __shared__ int fill[MAXNB];
    int t = threadIdx.x;
    int c0 = blockIdx.x * CHUNK;
    int c1 = min(c0 + CHUNK, E);
    for (int i = t; i < nb; i += 256) h[i] = 0;
    __syncthreads();
    for (int e = c0 + t; e < c1; e += 256)
        atomicAdd(&h[dst[e] >> 7], 1);
    __syncthreads();
    for (int i = t; i < nb; i += 256) {
        int c = h[i];
        base[i] = c ? atomicAdd(&bfill[i], c) : 0;
        fill[i] = 0;
    }
    __syncthreads();
    for (int e = c0 + t; e < c1; e += 256) {
        int d = dst[e];
        int b = d >> 7;
        int p = base[b] + atomicAdd(&fill[b], 1);
        bedge[p] = ((d & 127) << 17) | src[e];
    }
}

// ---------- B: per-bucket counting sort -> sorted_src, counts, row_start ----------
__global__ __launch_bounds__(256) void k_bsort(const int* __restrict__ bstart,
                                               const int* __restrict__ bedge,
                                               int* __restrict__ sorted_src,
                                               int* __restrict__ counts,
                                               int* __restrict__ row_start, int N) {
    __shared__ int hist[GB];
    __shared__ int fill[GB];
    __shared__ int stage[STAGE];
    int t = threadIdx.x;
    int b = blockIdx.x;
    int base_node = b << 7;
    int nn = min(GB, N - base_node);
    if (nn <= 0) return;
    int ebeg = bstart[b], eend = bstart[b + 1];
    if (t < GB) hist[t] = 0;
    __syncthreads();
    for (int e = ebeg + t; e < eend; e += 256)
        atomicAdd(&hist[bedge[e] >> 17], 1);
    __syncthreads();
    int c = (t < GB) ? hist[t] : 0;
    for (int off = 1; off < GB; off <<= 1) {
        int u = (t < GB && t >= off) ? hist[t - off] : 0;
        __syncthreads();
        if (t < GB) hist[t] += u;
        __syncthreads();
    }
    int excl = (t < GB) ? hist[t] - c : 0;
    if (t < nn) {
        counts[base_node + t] = c;
        row_start[base_node + t] = ebeg + excl;
        fill[t] = excl;
    }
    __syncthreads();
    for (int e = ebeg + t; e < eend; e += 256) {
        int v = bedge[e];
        int p = atomicAdd(&fill[v >> 17], 1);
        int s = v & 0x1FFFF;
        if (p < STAGE) stage[p] = s;
        else sorted_src[ebeg + p] = s;   // overflow fallback (never for uniform graph)
    }
    __syncthreads();
    int ecnt = eend - ebeg;
    int lim = min(ecnt, STAGE);
    for (int i = t; i < lim; i += 256)
        sorted_src[ebeg + i] = stage[i];
}

// dinv[i] = rsqrt(in_degree + self_loop)
__global__ void k_dinv(const int* __restrict__ counts, float* __restrict__ dinv, int n) {
    int i = blockIdx.x * blockDim.x + threadIdx.x;
    if (i < n) dinv[i] = rsqrtf((float)(counts[i] + 1));
}

// ---------- layer 1 transform: hs1 = (x @ W1) * dinv ----------
__global__ __launch_bounds__(256) void k_gemm1(const float* __restrict__ x,
                                               const float* __restrict__ W1,
                                               const float* __restrict__ dinv,
                                               float* __restrict__ hs1, int n) {
    __shared__ float w[FIN * FH];  // 8 KB
    int t = threadIdx.x;
    for (int i = t; i < FIN * FH; i += 256) w[i] = W1[i];
    __syncthreads();
    int r = t >> 4, j = t & 15;
    int row = blockIdx.x * 16 + r;
    if (row >= n) return;
    const float* xr = x + (long long)row * FIN;
    float acc = 0.0f;
#pragma unroll 8
    for (int k = 0; k < FIN; ++k) acc = fmaf(xr[k], w[k * FH + j], acc);
    hs1[row * FH + j] = acc * dinv[row];
}

// ---------- layer 1 gather + relu + bias ----------
__global__ __launch_bounds__(256) void k_gather1(const int* __restrict__ rs,
                                                 const int* __restrict__ cnt,
                                                 const int* __restrict__ ss,
                                                 const float* __restrict__ hs1,
                                                 const float* __restrict__ dinv,
                                                 const float* __restrict__ b1,
                                                 float* __restrict__ h1, int n) {
    int t = threadIdx.x;
    int lane = t & 63, g = lane >> 4, f = lane & 15;
    int node = blockIdx.x * 4 + (t >> 6);
    if (node >= n) return;
    int beg = rs[node], end = beg + cnt[node];
    float acc = 0.0f;
    for (int e = beg + g; e < end; e += 4) acc += hs1[ss[e] * FH + f];
    acc += __shfl_xor(acc, 16, 64);
    acc += __shfl_xor(acc, 32, 64);
    acc += hs1[node * FH + f];  // self-loop
    float v = fmaxf(fmaf(dinv[node], acc, b1[f]), 0.0f);
    if (g == 0) h1[node * FH + f] = v;
}

// ---------- layer 2 transform: hs2 = (h1 @ W2) * dinv ----------
__global__ __launch_bounds__(256) void k_gemm2(const float* __restrict__ h1,
                                               const float* __restrict__ W2,
                                               const float* __restrict__ dinv,
                                               float* __restrict__ hs2, int n) {
    __shared__ float w[FH * FO];  // 4 KB
    __shared__ float h[4][FH];
    int t = threadIdx.x;
    for (int i = t; i < FH * FO; i += 256) w[i] = W2[i];
    int r = t >> 6, f = t & 63;
    int row = blockIdx.x * 4 + r;
    bool valid = row < n;
    if (valid && f < FH) h[r][f] = h1[row * FH + f];
    __syncthreads();
    if (!valid) return;
    float acc = 0.0f;
#pragma unroll
    for (int j = 0; j < FH; ++j) acc = fmaf(h[r][j], w[j * FO + f], acc);
    hs2[row * FO + f] = acc * dinv[row];
}

// ---------- layer 2 gather + bias + log_softmax ----------
__global__ __launch_bounds__(256) void k_gather2(const int* __restrict__ rs,
                                                 const int* __restrict__ cnt,
                                                 const int* __restrict__ ss,
                                                 const float* __restrict__ hs2,
                                                 const float* __restrict__ dinv,
                                                 const float* __restrict__ b2,
                                                 float* __restrict__ out, int n) {
    int t = threadIdx.x;
    int lane = t & 63;
    int node = blockIdx.x * 4 + (t >> 6);
    if (node >= n) return;
    int beg = rs[node], end = beg + cnt[node];
    float acc = hs2[node * FO + lane];  // self-loop
    int e = beg;
    for (; e + 4 <= end; e += 4) {
        int s0 = ss[e], s1 = ss[e + 1], s2 = ss[e + 2], s3 = ss[e + 3];
        float v0 = hs2[s0 * FO + lane];
        float v1 = hs2[s1 * FO + lane];
        float v2 = hs2[s2 * FO + lane];
        float v3 = hs2[s3 * FO + lane];
        acc += (v0 + v1) + (v2 + v3);
    }
    for (; e < end; ++e) acc += hs2[ss[e] * FO + lane];
    float v = fmaf(dinv[node], acc, b2[lane]);
    float m = v;
#pragma unroll
    for (int off = 32; off >= 1; off >>= 1) m = fmaxf(m, __shfl_xor(m, off, 64));
    float ex = __expf(v - m);
#pragma unroll
    for (int off = 32; off >= 1; off >>= 1) ex += __shfl_xor(ex, off, 64);
    out[node * FO + lane] = v - m - __logf(ex);
}

extern "C" void kernel_launch(void* const* d_in, const int* in_sizes, int n_in,
                              void* d_out, int out_size, void* d_ws, size_t ws_size,
                              hipStream_t stream) {
    const float* x  = (const float*)d_in[0];
    const int*   ei = (const int*)d_in[1];
    const float* W1 = (const float*)d_in[2];
    const float* b1 = (const float*)d_in[3];
    const float* W2 = (const float*)d_in[4];
    const float* b2 = (const float*)d_in[5];
    float* out = (float*)d_out;

    int N = in_sizes[0] / FIN;   // 100000
    int E = in_sizes[1] / 2;     // 3200000
    const int* src = ei;
    const int* dst = ei + E;
    int nb = (N + GB - 1) / GB;  // 782

    // workspace layout (4B units):
    // bcnt[nb] | bstart[nb+1] | bfill[nb] | counts[N] | row_start[N] | sorted_src[E]
    // | dinv[N] | hs1[16N] | h1[16N] | union{ bedge[E] (early) / hs2[64N] (late) }
    int* bcnt       = (int*)d_ws;
    int* bstart     = bcnt + MAXNB;
    int* bfill      = bstart + MAXNB + 1;
    int* counts     = bfill + MAXNB;
    int* row_start  = counts + N;
    int* sorted_src = row_start + N;
    float* dinv = (float*)(sorted_src + E);
    float* hs1  = dinv + N;
    float* h1   = hs1 + 16LL * N;
    float* hs2  = h1 + 16LL * N;          // 64N floats
    int* bedge  = (int*)hs2;              // E ints, dead before hs2 is written

    k_zero<<<(nb + 255) / 256, 256, 0, stream>>>(bcnt, nb);
    k_bhist<<<256, 256, 0, stream>>>(dst, bcnt, E, nb);
    k_bscan<<<1, 1024, 0, stream>>>(bcnt, bstart, bfill, nb);
    k_bscatter<<<(E + CHUNK - 1) / CHUNK, 256, 0, stream>>>(src, dst, bfill, bedge, E, nb);
    k_bsort<<<nb, 256, 0, stream>>>(bstart, bedge, sorted_src, counts, row_start, N);
    k_dinv<<<(N + 255) / 256, 256, 0, stream>>>(counts, dinv, N);

    k_gemm1<<<(N + 15) / 16, 256, 0, stream>>>(x, W1, dinv, hs1, N);
    k_gather1<<<(N + 3) / 4, 256, 0, stream>>>(row_start, counts, sorted_src, hs1, dinv, b1, h1, N);
    k_gemm2<<<(N + 3) / 4, 256, 0, stream>>>(h1, W2, dinv, hs2, N);
    k_gather2<<<(N + 3) / 4, 256, 0, stream>>>(row_start, counts, sorted_src, hs2, dinv, b2, out, N);
}

// Round 4
// 415.669 us; speedup vs baseline: 2.8863x; 1.2348x over previous
//
#include <hip/hip_runtime.h>

#define FIN 128
#define FH  16
#define FO  64
#define GB  128        // nodes per bucket (pow2: bucket = dst>>7)
#define MAXNB 1024     // max buckets (N <= 131072)
#define CHUNK 8192     // edges per block in phase A3
#define STAGE 8192     // LDS staging capacity in phase B (mean bucket = 4092)

__global__ void k_zero(int* __restrict__ p, int n) {
    int i = blockIdx.x * blockDim.x + threadIdx.x;
    if (i < n) p[i] = 0;
}

// ---------- A1: bucket histogram (LDS-aggregated) ----------
__global__ __launch_bounds__(256) void k_bhist(const int* __restrict__ dst,
                                               int* __restrict__ bcnt, int E, int nb) {
    __shared__ int h[MAXNB];
    int t = threadIdx.x;
    for (int i = t; i < nb; i += 256) h[i] = 0;
    __syncthreads();
    int stride = gridDim.x * 256;
    for (int e = blockIdx.x * 256 + t; e < E; e += stride)
        atomicAdd(&h[dst[e] >> 7], 1);
    __syncthreads();
    for (int i = t; i < nb; i += 256)
        if (h[i]) atomicAdd(&bcnt[i], h[i]);
}

// ---------- A2: single-block exclusive scan of bucket counts ----------
__global__ __launch_bounds__(1024) void k_bscan(const int* __restrict__ bcnt,
                                                int* __restrict__ bstart,
                                                int* __restrict__ bfill, int nb) {
    __shared__ int s[1024];
    int t = threadIdx.x;
    int v = (t < nb) ? bcnt[t] : 0;
    s[t] = v;
    __syncthreads();
    for (int off = 1; off < 1024; off <<= 1) {
        int u = (t >= off) ? s[t - off] : 0;
        __syncthreads();
        s[t] += u;
        __syncthreads();
    }
    if (t < nb) { bstart[t] = s[t] - v; bfill[t] = s[t] - v; }
    if (t == nb - 1) bstart[nb] = s[t];
}

// ---------- A3: scatter packed edges into bucket segments ----------
// pack: (dst & 127) << 17 | src   (src < 2^17)
__global__ __launch_bounds__(256) void k_bscatter(const int* __restrict__ src,
                                                  const int* __restrict__ dst,
                                                  int* __restrict__ bfill,
                                                  int* __restrict__ bedge, int E, int nb) {
    __shared__ int h[MAXNB];
    __shared__ int base[MAXNB];
    __shared__ int fill[MAXNB];
    int t = threadIdx.x;
    int c0 = blockIdx.x * CHUNK;
    int c1 = min(c0 + CHUNK, E);
    for (int i = t; i < nb; i += 256) h[i] = 0;
    __syncthreads();
    for (int e = c0 + t; e < c1; e += 256)
        atomicAdd(&h[dst[e] >> 7], 1);
    __syncthreads();
    for (int i = t; i < nb; i += 256) {
        int c = h[i];
        base[i] = c ? atomicAdd(&bfill[i], c) : 0;
        fill[i] = 0;
    }
    __syncthreads();
    for (int e = c0 + t; e < c1; e += 256) {
        int d = dst[e];
        int b = d >> 7;
        int p = base[b] + atomicAdd(&fill[b], 1);
        bedge[p] = ((d & 127) << 17) | src[e];
    }
}

// ---------- B: per-bucket counting sort -> sorted_src, counts, row_start, dinv ----------
__global__ __launch_bounds__(256) void k_bsort(const int* __restrict__ bstart,
                                               const int* __restrict__ bedge,
                                               int* __restrict__ sorted_src,
                                               int* __restrict__ counts,
                                               int* __restrict__ row_start,
                                               float* __restrict__ dinv, int N) {
    __shared__ int hist[GB];
    __shared__ int fill[GB];
    __shared__ int stage[STAGE];
    int t = threadIdx.x;
    int b = blockIdx.x;
    int base_node = b << 7;
    int nn = min(GB, N - base_node);
    if (nn <= 0) return;
    int ebeg = bstart[b], eend = bstart[b + 1];
    if (t < GB) hist[t] = 0;
    __syncthreads();
    for (int e = ebeg + t; e < eend; e += 256)
        atomicAdd(&hist[bedge[e] >> 17], 1);
    __syncthreads();
    int c = (t < GB) ? hist[t] : 0;
    for (int off = 1; off < GB; off <<= 1) {
        int u = (t < GB && t >= off) ? hist[t - off] : 0;
        __syncthreads();
        if (t < GB) hist[t] += u;
        __syncthreads();
    }
    int excl = (t < GB) ? hist[t] - c : 0;
    if (t < nn) {
        counts[base_node + t] = c;
        row_start[base_node + t] = ebeg + excl;
        dinv[base_node + t] = rsqrtf((float)(c + 1));
        fill[t] = excl;
    }
    __syncthreads();
    for (int e = ebeg + t; e < eend; e += 256) {
        int v = bedge[e];
        int p = atomicAdd(&fill[v >> 17], 1);
        int s = v & 0x1FFFF;
        if (p < STAGE) stage[p] = s;
        else sorted_src[ebeg + p] = s;   // overflow fallback (never for uniform graph)
    }
    __syncthreads();
    int ecnt = eend - ebeg;
    int lim = min(ecnt, STAGE);
    for (int i = t; i < lim; i += 256)
        sorted_src[ebeg + i] = stage[i];
}

// ---------- layer 1 transform: hs1 = (x @ W1) * dinv ----------
__global__ __launch_bounds__(256) void k_gemm1(const float* __restrict__ x,
                                               const float* __restrict__ W1,
                                               const float* __restrict__ dinv,
                                               float* __restrict__ hs1, int n) {
    __shared__ float w[FIN * FH];  // 8 KB
    int t = threadIdx.x;
    for (int i = t; i < FIN * FH; i += 256) w[i] = W1[i];
    __syncthreads();
    int r = t >> 4, j = t & 15;
    int row = blockIdx.x * 16 + r;
    if (row >= n) return;
    const float* xr = x + (long long)row * FIN;
    float acc = 0.0f;
#pragma unroll 8
    for (int k = 0; k < FIN; ++k) acc = fmaf(xr[k], w[k * FH + j], acc);
    hs1[row * FH + j] = acc * dinv[row];
}

// ---------- layer 1 gather + relu + bias, pre-scaled for layer 2 ----------
// h1s[node] = relu(dinv*(self + sum_in) + b1) * dinv
__global__ __launch_bounds__(256) void k_gather1(const int* __restrict__ rs,
                                                 const int* __restrict__ cnt,
                                                 const int* __restrict__ ss,
                                                 const float* __restrict__ hs1,
                                                 const float* __restrict__ dinv,
                                                 const float* __restrict__ b1,
                                                 float* __restrict__ h1s, int n) {
    int t = threadIdx.x;
    int lane = t & 63, g = lane >> 4, f = lane & 15;
    int node = blockIdx.x * 4 + (t >> 6);
    if (node >= n) return;
    int beg = rs[node], end = beg + cnt[node];
    float acc = 0.0f;
    for (int e = beg + g; e < end; e += 4) acc += hs1[ss[e] * FH + f];
    acc += __shfl_xor(acc, 16, 64);
    acc += __shfl_xor(acc, 32, 64);
    acc += hs1[node * FH + f];  // self-loop
    float di = dinv[node];
    float v = fmaxf(fmaf(di, acc, b1[f]), 0.0f) * di;
    if (g == 0) h1s[node * FH + f] = v;
}

// ---------- layer 2: 16-dim gather, then fused (g @ W2)*dinv + b2 -> log_softmax ----------
__global__ __launch_bounds__(256) void k_agg2f(const int* __restrict__ rs,
                                               const int* __restrict__ cnt,
                                               const int* __restrict__ ss,
                                               const float* __restrict__ h1s,
                                               const float* __restrict__ dinv,
                                               const float* __restrict__ W2,
                                               const float* __restrict__ b2,
                                               float* __restrict__ out, int n) {
    int t = threadIdx.x;
    int lane = t & 63, g = lane >> 4, f = lane & 15;
    int node = blockIdx.x * 4 + (t >> 6);
    if (node >= n) return;
    float w[FH];  // W2 column `lane`
#pragma unroll
    for (int j = 0; j < FH; ++j) w[j] = W2[j * FO + lane];
    int beg = rs[node], end = beg + cnt[node];
    float acc = (g == 0) ? h1s[node * FH + f] : 0.0f;  // self-loop
    for (int e = beg + g; e < end; e += 4) acc += h1s[ss[e] * FH + f];
    acc += __shfl_xor(acc, 16, 64);
    acc += __shfl_xor(acc, 32, 64);
    // lane 16k+j now holds g16[j]; transform 16 -> 64
    float o = 0.0f;
#pragma unroll
    for (int j = 0; j < FH; ++j) o = fmaf(__shfl(acc, j, 16), w[j], o);
    float v = fmaf(dinv[node], o, b2[lane]);
    float m = v;
#pragma unroll
    for (int off = 32; off >= 1; off >>= 1) m = fmaxf(m, __shfl_xor(m, off, 64));
    float ex = __expf(v - m);
#pragma unroll
    for (int off = 32; off >= 1; off >>= 1) ex += __shfl_xor(ex, off, 64);
    out[node * FO + lane] = v - m - __logf(ex);
}

extern "C" void kernel_launch(void* const* d_in, const int* in_sizes, int n_in,
                              void* d_out, int out_size, void* d_ws, size_t ws_size,
                              hipStream_t stream) {
    const float* x  = (const float*)d_in[0];
    const int*   ei = (const int*)d_in[1];
    const float* W1 = (const float*)d_in[2];
    const float* b1 = (const float*)d_in[3];
    const float* W2 = (const float*)d_in[4];
    const float* b2 = (const float*)d_in[5];
    float* out = (float*)d_out;

    int N = in_sizes[0] / FIN;   // 100000
    int E = in_sizes[1] / 2;     // 3200000
    const int* src = ei;
    const int* dst = ei + E;
    int nb = (N + GB - 1) / GB;  // 782

    // workspace layout (4B units):
    // bcnt | bstart | bfill | counts[N] | row_start[N] | sorted_src[E] | bedge[E]
    // | dinv[N] | hs1[16N] | h1s[16N]
    int* bcnt       = (int*)d_ws;
    int* bstart     = bcnt + MAXNB;
    int* bfill      = bstart + MAXNB + 1;
    int* counts     = bfill + MAXNB;
    int* row_start  = counts + N;
    int* sorted_src = row_start + N;
    int* bedge      = sorted_src + E;
    float* dinv = (float*)(bedge + E);
    float* hs1  = dinv + N;
    float* h1s  = hs1 + 16LL * N;

    k_zero<<<(nb + 255) / 256, 256, 0, stream>>>(bcnt, nb);
    k_bhist<<<256, 256, 0, stream>>>(dst, bcnt, E, nb);
    k_bscan<<<1, 1024, 0, stream>>>(bcnt, bstart, bfill, nb);
    k_bscatter<<<(E + CHUNK - 1) / CHUNK, 256, 0, stream>>>(src, dst, bfill, bedge, E, nb);
    k_bsort<<<nb, 256, 0, stream>>>(bstart, bedge, sorted_src, counts, row_start, dinv, N);

    k_gemm1<<<(N + 15) / 16, 256, 0, stream>>>(x, W1, dinv, hs1, N);
    k_gather1<<<(N + 3) / 4, 256, 0, stream>>>(row_start, counts, sorted_src, hs1, dinv, b1, h1s, N);
    k_agg2f<<<(N + 3) / 4, 256, 0, stream>>>(row_start, counts, sorted_src, h1s, dinv, W2, b2, out, N);
}

// Round 5
// 325.546 us; speedup vs baseline: 3.6854x; 1.2768x over previous
//
#include <hip/hip_runtime.h>

#define FIN 128
#define FH  16
#define FO  64
#define GB  128        // nodes per bucket (pow2: bucket = dst>>7)
#define MAXNB 1024     // max buckets (N <= 131072)
#define CHUNK 8192     // edges per block in phase A3
#define STAGE 8192     // LDS staging capacity in phase B (mean bucket = 4092)

__device__ __forceinline__ unsigned pack_bf16x2(float a, float b) {
    unsigned ua = __float_as_uint(a), ub = __float_as_uint(b);
    ua = (ua + 0x7fffu + ((ua >> 16) & 1u)) >> 16;          // RNE
    ub = (ub + 0x7fffu + ((ub >> 16) & 1u)) >> 16;
    return ua | (ub << 16);
}

__device__ __forceinline__ float2 unpack_bf16x2(unsigned u) {
    float2 r;
    r.x = __uint_as_float(u << 16);
    r.y = __uint_as_float(u & 0xffff0000u);
    return r;
}

__global__ void k_zero(int* __restrict__ p, int n) {
    int i = blockIdx.x * blockDim.x + threadIdx.x;
    if (i < n) p[i] = 0;
}

// ---------- A1: bucket histogram (LDS-aggregated) ----------
__global__ __launch_bounds__(256) void k_bhist(const int* __restrict__ dst,
                                               int* __restrict__ bcnt, int E, int nb) {
    __shared__ int h[MAXNB];
    int t = threadIdx.x;
    for (int i = t; i < nb; i += 256) h[i] = 0;
    __syncthreads();
    int stride = gridDim.x * 256;
    for (int e = blockIdx.x * 256 + t; e < E; e += stride)
        atomicAdd(&h[dst[e] >> 7], 1);
    __syncthreads();
    for (int i = t; i < nb; i += 256)
        if (h[i]) atomicAdd(&bcnt[i], h[i]);
}

// ---------- A2: single-block exclusive scan of bucket counts ----------
__global__ __launch_bounds__(1024) void k_bscan(const int* __restrict__ bcnt,
                                                int* __restrict__ bstart,
                                                int* __restrict__ bfill, int nb) {
    __shared__ int s[1024];
    int t = threadIdx.x;
    int v = (t < nb) ? bcnt[t] : 0;
    s[t] = v;
    __syncthreads();
    for (int off = 1; off < 1024; off <<= 1) {
        int u = (t >= off) ? s[t - off] : 0;
        __syncthreads();
        s[t] += u;
        __syncthreads();
    }
    if (t < nb) { bstart[t] = s[t] - v; bfill[t] = s[t] - v; }
    if (t == nb - 1) bstart[nb] = s[t];
}

// ---------- A3: scatter packed edges into bucket segments ----------
// pack: (dst & 127) << 17 | src   (src < 2^17)
__global__ __launch_bounds__(256) void k_bscatter(const int* __restrict__ src,
                                                  const int* __restrict__ dst,
                                                  int* __restrict__ bfill,
                                                  int* __restrict__ bedge, int E, int nb) {
    __shared__ int h[MAXNB];
    __shared__ int base[MAXNB];
    __shared__ int fill[MAXNB];
    int t = threadIdx.x;
    int c0 = blockIdx.x * CHUNK;
    int c1 = min(c0 + CHUNK, E);
    for (int i = t; i < nb; i += 256) h[i] = 0;
    __syncthreads();
    for (int e = c0 + t; e < c1; e += 256)
        atomicAdd(&h[dst[e] >> 7], 1);
    __syncthreads();
    for (int i = t; i < nb; i += 256) {
        int c = h[i];
        base[i] = c ? atomicAdd(&bfill[i], c) : 0;
        fill[i] = 0;
    }
    __syncthreads();
    for (int e = c0 + t; e < c1; e += 256) {
        int d = dst[e];
        int b = d >> 7;
        int p = base[b] + atomicAdd(&fill[b], 1);
        bedge[p] = ((d & 127) << 17) | src[e];
    }
}

// ---------- B: per-bucket counting sort -> sorted_src, counts, row_start, dinv ----------
__global__ __launch_bounds__(256) void k_bsort(const int* __restrict__ bstart,
                                               const int* __restrict__ bedge,
                                               int* __restrict__ sorted_src,
                                               int* __restrict__ counts,
                                               int* __restrict__ row_start,
                                               float* __restrict__ dinv, int N) {
    __shared__ int hist[GB];
    __shared__ int fill[GB];
    __shared__ int stage[STAGE];
    int t = threadIdx.x;
    int b = blockIdx.x;
    int base_node = b << 7;
    int nn = min(GB, N - base_node);
    if (nn <= 0) return;
    int ebeg = bstart[b], eend = bstart[b + 1];
    if (t < GB) hist[t] = 0;
    __syncthreads();
    for (int e = ebeg + t; e < eend; e += 256)
        atomicAdd(&hist[bedge[e] >> 17], 1);
    __syncthreads();
    int c = (t < GB) ? hist[t] : 0;
    for (int off = 1; off < GB; off <<= 1) {
        int u = (t < GB && t >= off) ? hist[t - off] : 0;
        __syncthreads();
        if (t < GB) hist[t] += u;
        __syncthreads();
    }
    int excl = (t < GB) ? hist[t] - c : 0;
    if (t < nn) {
        counts[base_node + t] = c;
        row_start[base_node + t] = ebeg + excl;
        dinv[base_node + t] = rsqrtf((float)(c + 1));
        fill[t] = excl;
    }
    __syncthreads();
    for (int e = ebeg + t; e < eend; e += 256) {
        int v = bedge[e];
        int p = atomicAdd(&fill[v >> 17], 1);
        int s = v & 0x1FFFF;
        if (p < STAGE) stage[p] = s;
        else sorted_src[ebeg + p] = s;   // overflow fallback (never for uniform graph)
    }
    __syncthreads();
    int ecnt = eend - ebeg;
    int lim = min(ecnt, STAGE);
    for (int i = t; i < lim; i += 256)
        sorted_src[ebeg + i] = stage[i];
}

// ---------- layer 1 transform: hs1 = bf16((x @ W1) * dinv) ----------
__global__ __launch_bounds__(256) void k_gemm1(const float* __restrict__ x,
                                               const float* __restrict__ W1,
                                               const float* __restrict__ dinv,
                                               unsigned* __restrict__ hs1u, int n) {
    __shared__ float w[FIN * FH];  // 8 KB
    int t = threadIdx.x;
    for (int i = t; i < FIN * FH; i += 256) w[i] = W1[i];
    __syncthreads();
    int r = t >> 4, j = t & 15;
    int row = blockIdx.x * 16 + r;
    if (row >= n) return;
    const float* xr = x + (long long)row * FIN;
    float acc = 0.0f;
#pragma unroll 8
    for (int k = 0; k < FIN; ++k) acc = fmaf(xr[k], w[k * FH + j], acc);
    float v = acc * dinv[row];
    float v_hi = __shfl_xor(v, 1, 64);   // partner feature j^1
    if ((j & 1) == 0) hs1u[row * 8 + (j >> 1)] = pack_bf16x2(v, v_hi);
}

// ---------- layer 1 gather + relu + bias, pre-scaled for layer 2 (bf16 rows) ----------
// 8 groups of 8 lanes per node-wave; lane f2 covers features {2f2, 2f2+1}
__global__ __launch_bounds__(256) void k_gather1(const int* __restrict__ rs,
                                                 const int* __restrict__ cnt,
                                                 const int* __restrict__ ss,
                                                 const unsigned* __restrict__ hs1u,
                                                 const float* __restrict__ dinv,
                                                 const float* __restrict__ b1,
                                                 unsigned* __restrict__ h1su, int n) {
    int t = threadIdx.x;
    int lane = t & 63, g8 = lane >> 3, f2 = lane & 7;
    int node = blockIdx.x * 4 + (t >> 6);
    if (node >= n) return;
    int beg = rs[node], end = beg + cnt[node];
    float ax = 0.0f, ay = 0.0f;
    int e = beg + g8;
    for (; e + 8 < end; e += 16) {
        unsigned u0 = hs1u[ss[e] * 8 + f2];
        unsigned u1 = hs1u[ss[e + 8] * 8 + f2];
        float2 p0 = unpack_bf16x2(u0);
        float2 p1 = unpack_bf16x2(u1);
        ax += p0.x + p1.x; ay += p0.y + p1.y;
    }
    if (e < end) {
        float2 p = unpack_bf16x2(hs1u[ss[e] * 8 + f2]);
        ax += p.x; ay += p.y;
    }
#pragma unroll
    for (int off = 8; off <= 32; off <<= 1) {
        ax += __shfl_xor(ax, off, 64);
        ay += __shfl_xor(ay, off, 64);
    }
    float2 s = unpack_bf16x2(hs1u[node * 8 + f2]);  // self-loop
    ax += s.x; ay += s.y;
    float di = dinv[node];
    float v0 = fmaxf(fmaf(di, ax, b1[2 * f2]), 0.0f) * di;
    float v1 = fmaxf(fmaf(di, ay, b1[2 * f2 + 1]), 0.0f) * di;
    if (lane < 8) h1su[node * 8 + f2] = pack_bf16x2(v0, v1);
}

// ---------- layer 2: bf16 gather, fused (g @ W2)*dinv + b2 -> log_softmax ----------
__global__ __launch_bounds__(256) void k_agg2f(const int* __restrict__ rs,
                                               const int* __restrict__ cnt,
                                               const int* __restrict__ ss,
                                               const unsigned* __restrict__ h1su,
                                               const float* __restrict__ dinv,
                                               const float* __restrict__ W2,
                                               const float* __restrict__ b2,
                                               float* __restrict__ out, int n) {
    int t = threadIdx.x;
    int lane = t & 63, g8 = lane >> 3, f2 = lane & 7;
    int node = blockIdx.x * 4 + (t >> 6);
    if (node >= n) return;
    float w[FH];  // W2 column `lane`
#pragma unroll
    for (int j = 0; j < FH; ++j) w[j] = W2[j * FO + lane];
    int beg = rs[node], end = beg + cnt[node];
    float ax = 0.0f, ay = 0.0f;
    int e = beg + g8;
    for (; e + 8 < end; e += 16) {
        unsigned u0 = h1su[ss[e] * 8 + f2];
        unsigned u1 = h1su[ss[e + 8] * 8 + f2];
        float2 p0 = unpack_bf16x2(u0);
        float2 p1 = unpack_bf16x2(u1);
        ax += p0.x + p1.x; ay += p0.y + p1.y;
    }
    if (e < end) {
        float2 p = unpack_bf16x2(h1su[ss[e] * 8 + f2]);
        ax += p.x; ay += p.y;
    }
#pragma unroll
    for (int off = 8; off <= 32; off <<= 1) {
        ax += __shfl_xor(ax, off, 64);
        ay += __shfl_xor(ay, off, 64);
    }
    float2 s = unpack_bf16x2(h1su[node * 8 + f2]);  // self-loop
    ax += s.x; ay += s.y;
    // lane f2 holds pair (g[2f2], g[2f2+1]) in every 8-lane segment; 16 -> 64
    float o = 0.0f;
#pragma unroll
    for (int j = 0; j < 8; ++j) {
        o = fmaf(__shfl(ax, j, 8), w[2 * j], o);
        o = fmaf(__shfl(ay, j, 8), w[2 * j + 1], o);
    }
    float v = fmaf(dinv[node], o, b2[lane]);
    float m = v;
#pragma unroll
    for (int off = 32; off >= 1; off >>= 1) m = fmaxf(m, __shfl_xor(m, off, 64));
    float ex = __expf(v - m);
#pragma unroll
    for (int off = 32; off >= 1; off >>= 1) ex += __shfl_xor(ex, off, 64);
    out[node * FO + lane] = v - m - __logf(ex);
}

extern "C" void kernel_launch(void* const* d_in, const int* in_sizes, int n_in,
                              void* d_out, int out_size, void* d_ws, size_t ws_size,
                              hipStream_t stream) {
    const float* x  = (const float*)d_in[0];
    const int*   ei = (const int*)d_in[1];
    const float* W1 = (const float*)d_in[2];
    const float* b1 = (const float*)d_in[3];
    const float* W2 = (const float*)d_in[4];
    const float* b2 = (const float*)d_in[5];
    float* out = (float*)d_out;

    int N = in_sizes[0] / FIN;   // 100000
    int E = in_sizes[1] / 2;     // 3200000
    const int* src = ei;
    const int* dst = ei + E;
    int nb = (N + GB - 1) / GB;  // 782

    // workspace layout (4B units):
    // bcnt | bstart | bfill | counts[N] | row_start[N] | sorted_src[E] | bedge[E]
    // | dinv[N] | hs1u[8N] | h1su[8N]
    int* bcnt       = (int*)d_ws;
    int* bstart     = bcnt + MAXNB;
    int* bfill      = bstart + MAXNB + 1;
    int* counts     = bfill + MAXNB;
    int* row_start  = counts + N;
    int* sorted_src = row_start + N;
    int* bedge      = sorted_src + E;
    float* dinv     = (float*)(bedge + E);
    unsigned* hs1u  = (unsigned*)(dinv + N);
    unsigned* h1su  = hs1u + 8LL * N;

    k_zero<<<(nb + 255) / 256, 256, 0, stream>>>(bcnt, nb);
    k_bhist<<<256, 256, 0, stream>>>(dst, bcnt, E, nb);
    k_bscan<<<1, 1024, 0, stream>>>(bcnt, bstart, bfill, nb);
    k_bscatter<<<(E + CHUNK - 1) / CHUNK, 256, 0, stream>>>(src, dst, bfill, bedge, E, nb);
    k_bsort<<<nb, 256, 0, stream>>>(bstart, bedge, sorted_src, counts, row_start, dinv, N);

    k_gemm1<<<(N + 15) / 16, 256, 0, stream>>>(x, W1, dinv, hs1u, N);
    k_gather1<<<(N + 3) / 4, 256, 0, stream>>>(row_start, counts, sorted_src, hs1u, dinv, b1, h1su, N);
    k_agg2f<<<(N + 3) / 4, 256, 0, stream>>>(row_start, counts, sorted_src, h1su, dinv, W2, b2, out, N);
}